// Round 1
// 584.687 us; speedup vs baseline: 1.1217x; 1.1217x over previous
//
#include <hip/hip_runtime.h>

// SL-GAD forward, MFMA version. Inputs/outputs FLOAT32. Output: [L, scores(8192)].
#define BB 8192
#define KK 16
#define EE 64
#define FINN 300

typedef __attribute__((ext_vector_type(8))) short short8;
typedef __attribute__((ext_vector_type(4))) float f32x4;

__device__ __forceinline__ unsigned packbf(float a, float b) {  // 2xf32 -> bf16 pair (RNE)
  unsigned ua = __float_as_uint(a), ub = __float_as_uint(b);
  ua = (ua + 0x7fffu + ((ua >> 16) & 1u)) >> 16;
  ub = (ub + 0x7fffu + ((ub >> 16) & 1u)) >> 16;
  return ua | (ub << 16);
}
__device__ __forceinline__ float redC(float v) {  // sum over lane bits 0..3 (col group)
  v += __shfl_xor(v, 1); v += __shfl_xor(v, 2);
  v += __shfl_xor(v, 4); v += __shfl_xor(v, 8);
  return v;
}
__device__ __forceinline__ float redQ(float v) {  // sum over quads (lane bits 4,5)
  v += __shfl_xor(v, 16); v += __shfl_xor(v, 32);
  return v;
}
__device__ __forceinline__ float waveSum(float v) {
#pragma unroll
  for (int off = 32; off; off >>= 1) v += __shfl_xor(v, off);
  return v;
}
__device__ __forceinline__ double waveSumD(double v) {
#pragma unroll
  for (int off = 32; off; off >>= 1) v += __shfl_xor(v, off);
  return v;
}
__device__ __forceinline__ float logsig(float z) {  // log(sigmoid(z)), stable
  return fminf(z, 0.f) - log1pf(expf(-fabsf(z)));
}

// prep: W_enc (300x64 f32) -> bf16 B-fragment layout [nt(4)][kstep(10)][lane(64)]x16B
__global__ void prep_kernel(const float* __restrict__ Wenc, uint4* __restrict__ wB) {
  const int id = blockIdx.x * 256 + threadIdx.x;
  if (id >= 2560) return;
  const int lane = id & 63;
  const int step = (id >> 6) % 10;
  const int nt = id / 640;
  const int n = nt * 16 + (lane & 15);
  const int kb = step * 32 + (lane >> 4) * 8;   // B[k=kb+j][n], j=0..7 per lane
  float f[8];
#pragma unroll
  for (int j2 = 0; j2 < 8; ++j2) {
    const int k = kb + j2;
    f[j2] = (k < FINN) ? Wenc[k * 64 + n] : 0.f;
  }
  uint4 o;
  o.x = packbf(f[0], f[1]); o.y = packbf(f[2], f[3]);
  o.z = packbf(f[4], f[5]); o.w = packbf(f[6], f[7]);
  wB[id] = o;
}

// ---------------- encoder: FUSED over the 3 feature streams --------------------
// grid = 3*2048; blockIdx>>11 selects stream. block = 256 = 4 waves.
// LDS 40960 B (64 rows x 640 B, XOR-swizzled) -> exactly 4 blocks/CU.
__global__ __launch_bounds__(256, 4) void enc_kernel(
    const float* __restrict__ fpn, const float* __restrict__ fp1, const float* __restrict__ fp2,
    const float* __restrict__ wn, const float* __restrict__ w1, const float* __restrict__ w2,
    const int* __restrict__ sn, const int* __restrict__ s1, const int* __restrict__ s2,
    const int* __restrict__ dn, const int* __restrict__ d1, const int* __restrict__ d2,
    const uint4* __restrict__ wB, const float* __restrict__ benc,
    float* __restrict__ pooln, float* __restrict__ pool1, float* __restrict__ pool2,
    float* __restrict__ a1o, float* __restrict__ a2o,
    float* __restrict__ g1o, float* __restrict__ g2o,
    float* __restrict__ nd1o, float* __restrict__ nd2o)
{
  __shared__ char smem[40960];
  // phase 1: feat bf16, 64 rows x 320 cols (640 B stride; cols 300..319 zero).
  // XOR swizzle: physical byte = row*640 + (logical_off ^ ((row&7)<<4)); applied on
  // BOTH the staged write and the A-frag read (both-sides rule). 2-way banks = free.
  unsigned* featU = (unsigned*)smem;        // dword index: row*160 + (d ^ ((row&7)<<2))
  // phase 2 overlay:
  char* xBc = smem;                         // 16384 B: x bf16 B-frags [g][nt][lane]x16B
  float* AdjL = (float*)(smem + 16384);     // 4 x 256 f32 (dense adjacency, atomic build)
  char* AdjBc = smem + 20480;               // 4 x 16rows x 64B (bf16, s-padded to 32)
  float* coefL = (float*)(smem + 24576);    // 4 x 16 (Adj[0][s] * dinv[s])
  float* xAnch = (float*)(smem + 24832);    // 4 x 64 (x row 0 per graph, f32)

  const int tid = threadIdx.x, lane = tid & 63, wv = tid >> 6;
  const int q = lane >> 4, c = lane & 15;
  const int kf = blockIdx.x >> 11;          // stream: 0=n, 1=p1, 2=p2
  const int bg = blockIdx.x & 2047;
  const int b0 = bg * 4;

  const float* feat; const float* wedg; const int* src; const int* dst;
  float* pool_out; float* a_out; float* g_out; float* nd0_out;
  if (kf == 0) {
    feat = fpn; wedg = wn; src = sn; dst = dn;
    pool_out = pooln; a_out = nullptr; g_out = nullptr; nd0_out = nullptr;
  } else if (kf == 1) {
    feat = fp1; wedg = w1; src = s1; dst = d1;
    pool_out = pool1; a_out = a1o; g_out = g1o; nd0_out = nd1o;
  } else {
    feat = fp2; wedg = w2; src = s2; dst = d2;
    pool_out = pool2; a_out = a2o; g_out = g2o; nd0_out = nd2o;
  }

  // W B-frags for this wave's n-tile, held in VGPRs (L2-resident, no in-loop chain)
  uint4 bfr[10];
  {
    const uint4* p = wB + (wv * 10) * 64 + lane;
#pragma unroll
    for (int s = 0; s < 10; ++s) bfr[s] = p[s * 64];
  }
  // stage feat (76.8 KB f32 -> bf16 LDS), coalesced float4, swizzled write
  {
    const float4* gf = (const float4*)(feat + (size_t)b0 * (KK * FINN));
    for (int it = tid; it < 4800; it += 256) {
      const float4 v = gf[it];
      const int row = it / 75, c4 = it - row * 75;
      uint2 o;
      o.x = packbf(v.x, v.y);
      o.y = packbf(v.z, v.w);
      *(uint2*)&featU[row * 160 + ((c4 * 2) ^ ((row & 7) << 2))] = o;
    }
    for (int it = tid; it < 640; it += 256) {   // zero K-pad cols 300..319 (swizzled)
      const int row = it / 10, dlog = 150 + (it - row * 10);
      featU[row * 160 + (dlog ^ ((row & 7) << 2))] = 0;
    }
  }
  __syncthreads();

  // GEMM: acc[m] = feat[m-tile] @ Wenc[:, wv-tile]
  f32x4 acc[4];
#pragma unroll
  for (int m = 0; m < 4; ++m) acc[m] = (f32x4){0.f, 0.f, 0.f, 0.f};
  const int xr = (c & 7) << 4;  // (row&7)<<4 with row = m*16+c
#pragma unroll
  for (int s = 0; s < 10; ++s) {
    const short8 b8 = *(const short8*)&bfr[s];
#pragma unroll
    for (int m = 0; m < 4; ++m) {
      // A-frag: A[mrow=lane&15][k=q*8+j]; swizzled read matches swizzled write
      const short8 a8 = *(const short8*)(smem + (m * 16 + c) * 640 + ((s * 64 + q * 16) ^ xr));
      acc[m] = __builtin_amdgcn_mfma_f32_16x16x32_bf16(a8, b8, acc[m], 0, 0, 0);
    }
  }
  __syncthreads();  // all featA reads done before overlay writes

  // epilogue: x -> bf16 B-frag layout for the spmm MFMA; x row0 f32 for anchor
#pragma unroll
  for (int m = 0; m < 4; ++m) {
    // C layout: col=lane&15 (in n-tile wv), row=q*4+r (in m-tile m); s=4q+r -> lane'=(q>>1)*16+c, jj=4(q&1)+r
    unsigned* dp = (unsigned*)(xBc + ((m * 4 + wv) * 64 + (q >> 1) * 16 + c) * 16 + (q & 1) * 8);
    dp[0] = packbf(acc[m][0], acc[m][1]);
    dp[1] = packbf(acc[m][2], acc[m][3]);
    if (q == 0) xAnch[m * 64 + wv * 16 + c] = acc[m][0];  // row 4*0+0 = node 0
  }
  {
    const uint4 z = {0, 0, 0, 0};
    for (int i = tid; i < 512; i += 256)            // zero xB K-pad lanes 32..63
      ((uint4*)xBc)[(i >> 5) * 64 + 32 + (i & 31)] = z;
    for (int i = tid; i < 512; i += 256)            // zero AdjL (4KB) + AdjB (4KB)
      ((uint4*)(smem + 16384))[i] = z;
  }
  __syncthreads();

  // -------- phase 2: wave = graph g = wv, lane = edge then (quad,col) roles ------
  const int g = wv;
  const int bu = b0 + wv;
  const int se = src[bu * EE + lane];
  const int de = dst[bu * EE + lane];
  const float we = wedg[bu * EE + lane];

  float dinv_reg = 0.f;  // lane k<16 ends holding dinv_src[k]
#pragma unroll
  for (int k = 0; k < KK; ++k) {
    const int cnt = __popcll(__ballot(se == k));
    if (lane == k) dinv_reg = rsqrtf(fmaxf((float)cnt, 1.f));
  }
  if (nd0_out) {
    const int cd0 = __popcll(__ballot(de == 0));
    if (lane == 0) nd0_out[bu] = rsqrtf(fmaxf((float)cd0, 1.f));
  }
  atomicAdd(&AdjL[g * 256 + de * 16 + se], we);  // dense adjacency build (ds_add, block-local)
  __threadfence_block();
  {
    // AdjL -> AdjB bf16 (A-frag rows, s-dim padded to 32 with zeros).
    // Encoder spmm must treat x[0]=0 (fz): zero column s=0 in AdjB only.
    const f32x4 v = *(const f32x4*)(AdjL + g * 256 + lane * 4);
    const float v0 = ((lane & 3) == 0) ? 0.f : v[0];
    unsigned* w = (unsigned*)(AdjBc + g * 1024 + (lane >> 2) * 64 + (lane & 3) * 8);
    w[0] = packbf(v0, v[1]);
    w[1] = packbf(v[2], v[3]);
  }
  if (g_out && lane < KK)  // coef[s] = Adj[0][s] * dinv_src[s] (raw Adj row 0)
    coefL[g * 16 + lane] = AdjL[g * 256 + lane] * dinv_reg;
  __threadfence_block();

  // spmm: agg(16x64) = Adj(16x16,pad32) @ x(16x64,pad32) as 4 MFMA
  const short8 aAdj = *(const short8*)(AdjBc + g * 1024 + c * 64 + q * 16);
  float bj[4], h[4][4];
#pragma unroll
  for (int nt = 0; nt < 4; ++nt) bj[nt] = benc[nt * 16 + c];
#pragma unroll
  for (int nt = 0; nt < 4; ++nt) {
    const short8 xb = *(const short8*)(xBc + ((g * 4 + nt) * 64 + lane) * 16);
    f32x4 cc = (f32x4){0.f, 0.f, 0.f, 0.f};
    cc = __builtin_amdgcn_mfma_f32_16x16x32_bf16(aAdj, xb, cc, 0, 0, 0);
#pragma unroll
    for (int r = 0; r < 4; ++r) h[nt][r] = fmaxf(cc[r] + bj[nt], 0.f);  // node 4q+r, col nt*16+c
  }

  // pool = l2n(sum_k h) (mean's 1/16 cancels in l2n)
  float pl[4];
#pragma unroll
  for (int nt = 0; nt < 4; ++nt)
    pl[nt] = redQ(h[nt][0] + h[nt][1] + h[nt][2] + h[nt][3]);
  float pn2 = redC(pl[0] * pl[0] + pl[1] * pl[1] + pl[2] * pl[2] + pl[3] * pl[3]);
  const float pinv = 1.f / fmaxf(sqrtf(pn2), 1e-12f);
  if (q == 0)
#pragma unroll
    for (int nt = 0; nt < 4; ++nt)
      pool_out[(size_t)bu * 64 + nt * 16 + c] = pl[nt] * pinv;

  if (g_out) {  // gather: g[j] = sum_s coef[s] * l2n(h)[s][j]
    float rnv[4];
#pragma unroll
    for (int r = 0; r < 4; ++r) {
      float s2 = redC(h[0][r] * h[0][r] + h[1][r] * h[1][r] +
                      h[2][r] * h[2][r] + h[3][r] * h[3][r]);
      rnv[r] = 1.f / fmaxf(sqrtf(s2), 1e-12f);
    }
    float gp[4] = {0.f, 0.f, 0.f, 0.f};
#pragma unroll
    for (int r = 0; r < 4; ++r) {
      const float cf = coefL[g * 16 + q * 4 + r] * rnv[r];
#pragma unroll
      for (int nt = 0; nt < 4; ++nt) gp[nt] = fmaf(cf, h[nt][r], gp[nt]);
    }
#pragma unroll
    for (int nt = 0; nt < 4; ++nt) gp[nt] = redQ(gp[nt]);
    if (q == 1)
#pragma unroll
      for (int nt = 0; nt < 4; ++nt)
        g_out[(size_t)bu * 64 + nt * 16 + c] = gp[nt];
  }
  if (a_out) {  // anchor = l2n(relu(x[0] + b))
    float av[4], an2 = 0.f;
#pragma unroll
    for (int nt = 0; nt < 4; ++nt) {
      av[nt] = fmaxf(xAnch[g * 64 + nt * 16 + c] + bj[nt], 0.f);
      an2 += av[nt] * av[nt];
    }
    an2 = redC(an2);
    const float ainv = 1.f / fmaxf(sqrtf(an2), 1e-12f);
    if (q == 2)
#pragma unroll
      for (int nt = 0; nt < 4; ++nt)
        a_out[(size_t)bu * 64 + nt * 16 + c] = av[nt] * ainv;
  }
}

// ------- decoder anchor + per-graph loss, FUSED over both streams --------------
// One W_dec element load feeds both g1 and g2 streams (halves the L2 stream).
__global__ __launch_bounds__(256) void dec_kernel(
    const float* __restrict__ g1b, const float* __restrict__ g2b,
    const float* __restrict__ nd1b, const float* __restrict__ nd2b,
    const float* __restrict__ Wdec, const float* __restrict__ bdec,
    const float* __restrict__ feat1, const float* __restrict__ feat2,
    float* __restrict__ dArr1, float* __restrict__ dArr2)
{
  __shared__ float red[16];
  __shared__ float invA_s, invB_s;
  const int t = threadIdx.x, b = blockIdx.x;
  const float gva = g1b[(size_t)b * 64 + (t & 63)];  // g held across wave, shfl-broadcast
  const float gvb = g2b[(size_t)b * 64 + (t & 63)];
  const float nda = nd1b[b], ndb = nd2b[b];
  const int f0 = t, f1 = t + 256;
  const bool has1 = (f1 < FINN);
  float ya0 = 0.f, ya1 = 0.f, yb0 = 0.f, yb1 = 0.f;
  for (int jj = 0; jj < 64; ++jj) {
    const float w0 = Wdec[jj * FINN + f0];
    const float ga = __shfl(gva, jj), gb = __shfl(gvb, jj);
    ya0 = fmaf(ga, w0, ya0);
    yb0 = fmaf(gb, w0, yb0);
    if (has1) {
      const float w1 = Wdec[jj * FINN + f1];
      ya1 = fmaf(ga, w1, ya1);
      yb1 = fmaf(gb, w1, yb1);
    }
  }
  const float bd0 = bdec[f0];
  const float bd1 = has1 ? bdec[f1] : 0.f;
  const float aa0 = fmaxf(ya0 * nda + bd0, 0.f);
  const float aa1 = has1 ? fmaxf(ya1 * nda + bd1, 0.f) : 0.f;
  const float ab0 = fmaxf(yb0 * ndb + bd0, 0.f);
  const float ab1 = has1 ? fmaxf(yb1 * ndb + bd1, 0.f) : 0.f;
  float sA = waveSum(aa0 * aa0 + aa1 * aa1);
  float sB = waveSum(ab0 * ab0 + ab1 * ab1);
  if ((t & 63) == 0) { red[t >> 6] = sA; red[8 + (t >> 6)] = sB; }
  __syncthreads();
  if (t == 0) {
    invA_s = 1.f / fmaxf(sqrtf(red[0] + red[1] + red[2] + red[3]), 1e-12f);
    invB_s = 1.f / fmaxf(sqrtf(red[8] + red[9] + red[10] + red[11]), 1e-12f);
  }
  __syncthreads();
  const float invA = invA_s, invB = invB_s;
  const float* __restrict__ ori1 = feat1 + (size_t)b * KK * FINN;  // row 0
  const float* __restrict__ ori2 = feat2 + (size_t)b * KK * FINN;
  const float dA0 = aa0 * invA - ori1[f0];
  const float dA1 = has1 ? (aa1 * invA - ori1[f1]) : 0.f;
  const float dB0 = ab0 * invB - ori2[f0];
  const float dB1 = has1 ? (ab1 * invB - ori2[f1]) : 0.f;
  float sdA = waveSum(dA0 * dA0 + dA1 * dA1);
  float sdB = waveSum(dB0 * dB0 + dB1 * dB1);
  if ((t & 63) == 0) { red[t >> 6] = sdA; red[8 + (t >> 6)] = sdB; }
  __syncthreads();
  if (t == 0) {
    dArr1[b] = red[0] + red[1] + red[2] + red[3];
    dArr2[b] = red[8] + red[9] + red[10] + red[11];
  }
}

// ---------------- bilinear discriminator (NO global atomics) ---------------------
__global__ __launch_bounds__(256) void bil_kernel(
    const float* __restrict__ pool1, const float* __restrict__ pool2,
    const float* __restrict__ pooln, const float* __restrict__ a1b,
    const float* __restrict__ a2b, const float* __restrict__ Wbil,
    const float* __restrict__ bbil, float* __restrict__ contr,
    float* __restrict__ tArr1, float* __restrict__ tArr2)
{
  const int tid = threadIdx.x, wv = tid >> 6, j = tid & 63;
  const int bu = blockIdx.x * 4 + wv;
  const float p1 = pool1[(size_t)bu * 64 + j];
  const float p2 = pool2[(size_t)bu * 64 + j];
  const float pn = pooln[(size_t)bu * 64 + j];
  const float A1 = a1b[(size_t)bu * 64 + j];
  const float A2 = a2b[(size_t)bu * 64 + j];
  float v1 = 0.f, v2 = 0.f, vn = 0.f;
  for (int jj = 0; jj < 64; ++jj) {
    const float wr = Wbil[jj * 64 + j];  // coalesced row
    v1 = fmaf(__shfl(p1, jj), wr, v1);
    v2 = fmaf(__shfl(p2, jj), wr, v2);
    vn = fmaf(__shfl(pn, jj), wr, vn);
  }
  const float d11 = waveSum(v1 * A1);
  const float d22 = waveSum(v2 * A2);
  const float dn1 = waveSum(vn * A1);
  const float dn2 = waveSum(vn * A2);
  if (j == 0) {
    const float bb = bbil[0];
    const float z11 = d11 + bb, z22 = d22 + bb, zn1 = dn1 + bb, zn2 = dn2 + bb;
    const float ps1 = 1.f / (1.f + expf(-z11));
    const float ps2 = 1.f / (1.f + expf(-z22));
    const float ns1 = 1.f / (1.f + expf(-zn1));
    const float ns2 = 1.f / (1.f + expf(-zn2));
    contr[bu] = (ns1 - ps1 + 1.f) * 0.5f + (ns2 - ps2 + 1.f) * 0.5f;
    tArr1[bu] = logsig(z11) + logsig(-zn1);
    tArr2[bu] = logsig(z22) + logsig(-zn2);
  }
}

// ------- reduction + finalize FUSED: 4 x BB floats -> L, genw (one block) -------
__global__ __launch_bounds__(1024) void redfin_kernel(const float* __restrict__ parts,
                                                      float* __restrict__ genw,
                                                      float* __restrict__ out)
{
  __shared__ double sred[16];
  const int t = threadIdx.x, lane = t & 63, wv = t >> 6;  // 16 waves
  const int seg = t >> 8;                                 // 4 waves per segment
  const float* __restrict__ p = parts + (size_t)seg * BB;
  double s = 0.0;
  for (int i = (t & 255); i < BB; i += 256) s += (double)p[i];
  s = waveSumD(s);
  if (lane == 0) sred[wv] = s;
  __syncthreads();
  if (t == 0) {
    const double T1 = sred[0] + sred[1] + sred[2] + sred[3];
    const double T2 = sred[4] + sred[5] + sred[6] + sred[7];
    const double S1d = sred[8] + sred[9] + sred[10] + sred[11];
    const double S2d = sred[12] + sred[13] + sred[14] + sred[15];
    const double m1 = S1d / (double)BB, m2 = S2d / (double)BB;
    const double Lcon = -(m1 + m2) * 0.25;
    const double Lgen = (T1 + T2) / (2.0 * (double)BB * (double)FINN);
    out[0] = (float)(Lcon + 0.6 * Lgen);
    genw[0] = (float)((sqrt(T1) + sqrt(T2)) / (2.0 * sqrt((double)FINN)));
  }
}

__global__ void score_kernel(const float* __restrict__ contr, const float* __restrict__ genw,
                             float* __restrict__ out)
{
  const int i = blockIdx.x * blockDim.x + threadIdx.x;
  if (i < BB) out[1 + i] = fmaf(0.6f, genw[0], contr[i]);
}

extern "C" void kernel_launch(void* const* d_in, const int* in_sizes, int n_in,
                              void* d_out, int out_size, void* d_ws, size_t ws_size,
                              hipStream_t stream)
{
  const float* feat_p1 = (const float*)d_in[0];
  const float* feat_p2 = (const float*)d_in[1];
  const float* feat_n  = (const float*)d_in[2];
  const float* w_p1 = (const float*)d_in[3];
  const float* w_p2 = (const float*)d_in[4];
  const float* w_n  = (const float*)d_in[5];
  const float* W_enc = (const float*)d_in[6];
  const float* b_enc = (const float*)d_in[7];
  const float* W_dec = (const float*)d_in[8];
  const float* b_dec = (const float*)d_in[9];
  const float* W_bil = (const float*)d_in[10];
  const float* b_bil = (const float*)d_in[11];
  const int* src_p1 = (const int*)d_in[12];
  const int* dst_p1 = (const int*)d_in[13];
  const int* src_p2 = (const int*)d_in[14];
  const int* dst_p2 = (const int*)d_in[15];
  const int* src_n  = (const int*)d_in[16];
  const int* dst_n  = (const int*)d_in[17];
  float* out = (float*)d_out;

  float* genw = (float*)((char*)d_ws + 32);
  uint4* wsB = (uint4*)((char*)d_ws + 1024);             // 40960 B W_enc frags
  float* fws = (float*)((char*)d_ws + 49152);
  float* pool1 = fws;
  float* pool2 = pool1 + (size_t)BB * 64;
  float* pooln = pool2 + (size_t)BB * 64;
  float* a1 = pooln + (size_t)BB * 64;
  float* a2 = a1 + (size_t)BB * 64;
  float* g1 = a2 + (size_t)BB * 64;
  float* g2 = g1 + (size_t)BB * 64;
  float* nd01 = g2 + (size_t)BB * 64;
  float* nd02 = nd01 + BB;
  float* contr = nd02 + BB;
  float* parts = contr + BB;              // [dArr1 | dArr2 | tArr1 | tArr2], 4*BB
  float* dArr1 = parts;
  float* dArr2 = parts + BB;
  float* tArr1 = parts + 2 * BB;
  float* tArr2 = parts + 3 * BB;

  hipLaunchKernelGGL(prep_kernel, dim3(10), dim3(256), 0, stream, W_enc, wsB);
  hipLaunchKernelGGL(enc_kernel, dim3(3 * BB / 4), dim3(256), 0, stream,
                     feat_n, feat_p1, feat_p2,
                     w_n, w_p1, w_p2,
                     src_n, src_p1, src_p2,
                     dst_n, dst_p1, dst_p2,
                     wsB, b_enc,
                     pooln, pool1, pool2,
                     a1, a2, g1, g2, nd01, nd02);
  hipLaunchKernelGGL(dec_kernel, dim3(BB), dim3(256), 0, stream,
                     g1, g2, nd01, nd02, W_dec, b_dec, feat_p1, feat_p2, dArr1, dArr2);
  hipLaunchKernelGGL(bil_kernel, dim3(BB / 4), dim3(256), 0, stream,
                     pool1, pool2, pooln, a1, a2, W_bil, b_bil, contr, tArr1, tArr2);
  hipLaunchKernelGGL(redfin_kernel, dim3(1), dim3(1024), 0, stream, parts, genw, out);
  hipLaunchKernelGGL(score_kernel, dim3((BB + 255) / 256), dim3(256), 0, stream,
                     contr, genw, out);
}

// Round 2
// 559.016 us; speedup vs baseline: 1.1733x; 1.0459x over previous
//
#include <hip/hip_runtime.h>

// SL-GAD forward, MFMA version. Inputs/outputs FLOAT32. Output: [L, scores(8192)].
#define BB 8192
#define KK 16
#define EE 64
#define FINN 300

typedef __attribute__((ext_vector_type(8))) short short8;
typedef __attribute__((ext_vector_type(4))) float f32x4;

__device__ __forceinline__ unsigned short bf16r(float x) {  // f32 -> bf16 (RNE, native cvt)
  return __builtin_bit_cast(unsigned short, (__bf16)x);
}
__device__ __forceinline__ unsigned packbf(float a, float b) {  // 2xf32 -> bf16 pair
  return (unsigned)bf16r(a) | ((unsigned)bf16r(b) << 16);
}
__device__ __forceinline__ float redC(float v) {  // sum over lane bits 0..3 (col group)
  v += __shfl_xor(v, 1); v += __shfl_xor(v, 2);
  v += __shfl_xor(v, 4); v += __shfl_xor(v, 8);
  return v;
}
__device__ __forceinline__ float redQ(float v) {  // sum over quads (lane bits 4,5)
  v += __shfl_xor(v, 16); v += __shfl_xor(v, 32);
  return v;
}
__device__ __forceinline__ float waveSum(float v) {
#pragma unroll
  for (int off = 32; off; off >>= 1) v += __shfl_xor(v, off);
  return v;
}
__device__ __forceinline__ double waveSumD(double v) {
#pragma unroll
  for (int off = 32; off; off >>= 1) v += __shfl_xor(v, off);
  return v;
}
__device__ __forceinline__ float logsig(float z) {  // log(sigmoid(z)), stable
  return fminf(z, 0.f) - log1pf(expf(-fabsf(z)));
}

// prep: W_enc (300x64 f32) -> bf16 B-fragment layout [nt(4)][kstep(10)][lane(64)]x16B
__global__ void prep_kernel(const float* __restrict__ Wenc, uint4* __restrict__ wB) {
  const int id = blockIdx.x * 256 + threadIdx.x;
  if (id >= 2560) return;
  const int lane = id & 63;
  const int step = (id >> 6) % 10;
  const int nt = id / 640;
  const int n = nt * 16 + (lane & 15);
  const int kb = step * 32 + (lane >> 4) * 8;   // B[k=kb+j][n], j=0..7 per lane
  float f[8];
#pragma unroll
  for (int j2 = 0; j2 < 8; ++j2) {
    const int k = kb + j2;
    f[j2] = (k < FINN) ? Wenc[k * 64 + n] : 0.f;
  }
  uint4 o;
  o.x = packbf(f[0], f[1]); o.y = packbf(f[2], f[3]);
  o.z = packbf(f[4], f[5]); o.w = packbf(f[6], f[7]);
  wB[id] = o;
}

// ---------------- encoder: FUSED over the 3 feature streams --------------------
// grid = 3*2048; blockIdx>>11 selects stream. block = 256 = 4 waves.
// Feat staged in TWO 32-row half-tiles through one 20 KB buffer -> LDS 25856 B
// -> 6 blocks/CU (75% occupancy ceiling, was 4 blocks = 50%).
__global__ __launch_bounds__(256, 6) void enc_kernel(
    const float* __restrict__ fpn, const float* __restrict__ fp1, const float* __restrict__ fp2,
    const float* __restrict__ wn, const float* __restrict__ w1, const float* __restrict__ w2,
    const int* __restrict__ sn, const int* __restrict__ s1, const int* __restrict__ s2,
    const int* __restrict__ dn, const int* __restrict__ d1, const int* __restrict__ d2,
    const uint4* __restrict__ wB, const float* __restrict__ benc,
    float* __restrict__ pooln, float* __restrict__ pool1, float* __restrict__ pool2,
    float* __restrict__ a1o, float* __restrict__ a2o,
    float* __restrict__ g1o, float* __restrict__ g2o,
    float* __restrict__ nd1o, float* __restrict__ nd2o)
{
  __shared__ char smem[25856];
  // staging: 32 rows x 320 bf16 (640 B stride; cols 300..319 zero), XOR-swizzled:
  // dword index = row*160 + (d ^ ((row&7)<<2)); same swizzle on write and read.
  unsigned* featU = (unsigned*)smem;
  // phase 2 overlay:
  char* xBc = smem;                         // 16384 B: x bf16 B-frags [g][nt][lane]x16B
  float* AdjL = (float*)(smem + 16384);     // 4 x 256 f32 (dense adjacency, atomic build)
  char* AdjBc = smem + 20480;               // 4 x 16rows x 64B (bf16, s-padded to 32)
  float* coefL = (float*)(smem + 24576);    // 4 x 16 (Adj[0][s] * dinv[s])
  float* xAnch = (float*)(smem + 24832);    // 4 x 64 (x row 0 per graph, f32)

  const int tid = threadIdx.x, lane = tid & 63, wv = tid >> 6;
  const int q = lane >> 4, c = lane & 15;
  const int kf = blockIdx.x >> 11;          // stream: 0=n, 1=p1, 2=p2
  const int bg = blockIdx.x & 2047;
  const int b0 = bg * 4;

  const float* feat; const float* wedg; const int* src; const int* dst;
  float* pool_out; float* a_out; float* g_out; float* nd0_out;
  if (kf == 0) {
    feat = fpn; wedg = wn; src = sn; dst = dn;
    pool_out = pooln; a_out = nullptr; g_out = nullptr; nd0_out = nullptr;
  } else if (kf == 1) {
    feat = fp1; wedg = w1; src = s1; dst = d1;
    pool_out = pool1; a_out = a1o; g_out = g1o; nd0_out = nd1o;
  } else {
    feat = fp2; wedg = w2; src = s2; dst = d2;
    pool_out = pool2; a_out = a2o; g_out = g2o; nd0_out = nd2o;
  }

  // W B-frags for this wave's n-tile, held in VGPRs (L2-resident, no in-loop chain)
  uint4 bfr[10];
  {
    const uint4* p = wB + (wv * 10) * 64 + lane;
#pragma unroll
    for (int s = 0; s < 10; ++s) bfr[s] = p[s * 64];
  }
  const float4* gf = (const float4*)(feat + (size_t)b0 * (KK * FINN));

  // ---- stage A: logical rows 0..31 (graphs 0,1)
  for (int it = tid; it < 2400; it += 256) {
    const float4 v = gf[it];
    const int row = it / 75, c4 = it - row * 75;
    uint2 o;
    o.x = packbf(v.x, v.y);
    o.y = packbf(v.z, v.w);
    *(uint2*)&featU[row * 160 + ((c4 * 2) ^ ((row & 7) << 2))] = o;
  }
  for (int it = tid; it < 320; it += 256) {   // zero K-pad cols 300..319 (stays zero for half B)
    const int row = it / 10, dlog = 150 + (it - row * 10);
    featU[row * 160 + (dlog ^ ((row & 7) << 2))] = 0;
  }
  __syncthreads();

  f32x4 acc[4];
#pragma unroll
  for (int m = 0; m < 4; ++m) acc[m] = (f32x4){0.f, 0.f, 0.f, 0.f};
  const int xr = (c & 7) << 4;  // (row&7)<<4 with row = m*16+c (m*16 == 0 mod 8)

  // GEMM half A: m-tiles 0,1
#pragma unroll
  for (int s = 0; s < 10; ++s) {
    const short8 b8 = *(const short8*)&bfr[s];
#pragma unroll
    for (int m = 0; m < 2; ++m) {
      const short8 a8 = *(const short8*)(smem + (m * 16 + c) * 640 + ((s * 64 + q * 16) ^ xr));
      acc[m] = __builtin_amdgcn_mfma_f32_16x16x32_bf16(a8, b8, acc[m], 0, 0, 0);
    }
  }
  __syncthreads();  // half-A reads done before overwrite

  // ---- stage B: logical rows 32..63 (graphs 2,3) -> physical rows 0..31
  for (int it = tid; it < 2400; it += 256) {
    const float4 v = gf[2400 + it];
    const int row = it / 75, c4 = it - row * 75;   // physical row; (row&7) == (logical&7)
    uint2 o;
    o.x = packbf(v.x, v.y);
    o.y = packbf(v.z, v.w);
    *(uint2*)&featU[row * 160 + ((c4 * 2) ^ ((row & 7) << 2))] = o;
  }
  __syncthreads();

  // GEMM half B: m-tiles 2,3 (physical rows 0..31)
#pragma unroll
  for (int s = 0; s < 10; ++s) {
    const short8 b8 = *(const short8*)&bfr[s];
#pragma unroll
    for (int m = 2; m < 4; ++m) {
      const short8 a8 = *(const short8*)(smem + ((m - 2) * 16 + c) * 640 + ((s * 64 + q * 16) ^ xr));
      acc[m] = __builtin_amdgcn_mfma_f32_16x16x32_bf16(a8, b8, acc[m], 0, 0, 0);
    }
  }
  __syncthreads();  // all featA reads done before overlay writes

  // epilogue: x -> bf16 B-frag layout for the spmm MFMA; x row0 f32 for anchor
#pragma unroll
  for (int m = 0; m < 4; ++m) {
    // C layout: col=lane&15 (in n-tile wv), row=q*4+r (in m-tile m); s=4q+r -> lane'=(q>>1)*16+c, jj=4(q&1)+r
    unsigned* dp = (unsigned*)(xBc + ((m * 4 + wv) * 64 + (q >> 1) * 16 + c) * 16 + (q & 1) * 8);
    dp[0] = packbf(acc[m][0], acc[m][1]);
    dp[1] = packbf(acc[m][2], acc[m][3]);
    if (q == 0) xAnch[m * 64 + wv * 16 + c] = acc[m][0];  // row 4*0+0 = node 0
  }
  {
    const uint4 z = {0, 0, 0, 0};
    for (int i = tid; i < 512; i += 256)            // zero xB K-pad lanes 32..63
      ((uint4*)xBc)[(i >> 5) * 64 + 32 + (i & 31)] = z;
    for (int i = tid; i < 512; i += 256)            // zero AdjL (4KB) + AdjB (4KB)
      ((uint4*)(smem + 16384))[i] = z;
  }
  __syncthreads();

  // -------- phase 2: wave = graph g = wv, lane = edge then (quad,col) roles ------
  const int g = wv;
  const int bu = b0 + wv;
  const int se = src[bu * EE + lane];
  const int de = dst[bu * EE + lane];
  const float we = wedg[bu * EE + lane];

  float dinv_reg = 0.f;  // lane k<16 ends holding dinv_src[k]
#pragma unroll
  for (int k = 0; k < KK; ++k) {
    const int cnt = __popcll(__ballot(se == k));
    if (lane == k) dinv_reg = rsqrtf(fmaxf((float)cnt, 1.f));
  }
  if (nd0_out) {
    const int cd0 = __popcll(__ballot(de == 0));
    if (lane == 0) nd0_out[bu] = rsqrtf(fmaxf((float)cd0, 1.f));
  }
  atomicAdd(&AdjL[g * 256 + de * 16 + se], we);  // dense adjacency build (ds_add, block-local)
  __threadfence_block();
  {
    // AdjL -> AdjB bf16 (A-frag rows, s-dim padded to 32 with zeros).
    // Encoder spmm must treat x[0]=0 (fz): zero column s=0 in AdjB only.
    const f32x4 v = *(const f32x4*)(AdjL + g * 256 + lane * 4);
    const float v0 = ((lane & 3) == 0) ? 0.f : v[0];
    unsigned* w = (unsigned*)(AdjBc + g * 1024 + (lane >> 2) * 64 + (lane & 3) * 8);
    w[0] = packbf(v0, v[1]);
    w[1] = packbf(v[2], v[3]);
  }
  if (g_out && lane < KK)  // coef[s] = Adj[0][s] * dinv_src[s] (raw Adj row 0)
    coefL[g * 16 + lane] = AdjL[g * 256 + lane] * dinv_reg;
  __threadfence_block();

  // spmm: agg(16x64) = Adj(16x16,pad32) @ x(16x64,pad32) as 4 MFMA
  const short8 aAdj = *(const short8*)(AdjBc + g * 1024 + c * 64 + q * 16);
  float bj[4], h[4][4];
#pragma unroll
  for (int nt = 0; nt < 4; ++nt) bj[nt] = benc[nt * 16 + c];
#pragma unroll
  for (int nt = 0; nt < 4; ++nt) {
    const short8 xb = *(const short8*)(xBc + ((g * 4 + nt) * 64 + lane) * 16);
    f32x4 cc = (f32x4){0.f, 0.f, 0.f, 0.f};
    cc = __builtin_amdgcn_mfma_f32_16x16x32_bf16(aAdj, xb, cc, 0, 0, 0);
#pragma unroll
    for (int r = 0; r < 4; ++r) h[nt][r] = fmaxf(cc[r] + bj[nt], 0.f);  // node 4q+r, col nt*16+c
  }

  // pool = l2n(sum_k h) (mean's 1/16 cancels in l2n)
  float pl[4];
#pragma unroll
  for (int nt = 0; nt < 4; ++nt)
    pl[nt] = redQ(h[nt][0] + h[nt][1] + h[nt][2] + h[nt][3]);
  float pn2 = redC(pl[0] * pl[0] + pl[1] * pl[1] + pl[2] * pl[2] + pl[3] * pl[3]);
  const float pinv = 1.f / fmaxf(sqrtf(pn2), 1e-12f);
  if (q == 0)
#pragma unroll
    for (int nt = 0; nt < 4; ++nt)
      pool_out[(size_t)bu * 64 + nt * 16 + c] = pl[nt] * pinv;

  if (g_out) {  // gather: g[j] = sum_s coef[s] * l2n(h)[s][j]
    float rnv[4];
#pragma unroll
    for (int r = 0; r < 4; ++r) {
      float s2 = redC(h[0][r] * h[0][r] + h[1][r] * h[1][r] +
                      h[2][r] * h[2][r] + h[3][r] * h[3][r]);
      rnv[r] = 1.f / fmaxf(sqrtf(s2), 1e-12f);
    }
    float gp[4] = {0.f, 0.f, 0.f, 0.f};
#pragma unroll
    for (int r = 0; r < 4; ++r) {
      const float cf = coefL[g * 16 + q * 4 + r] * rnv[r];
#pragma unroll
      for (int nt = 0; nt < 4; ++nt) gp[nt] = fmaf(cf, h[nt][r], gp[nt]);
    }
#pragma unroll
    for (int nt = 0; nt < 4; ++nt) gp[nt] = redQ(gp[nt]);
    if (q == 1)
#pragma unroll
      for (int nt = 0; nt < 4; ++nt)
        g_out[(size_t)bu * 64 + nt * 16 + c] = gp[nt];
  }
  if (a_out) {  // anchor = l2n(relu(x[0] + b))
    float av[4], an2 = 0.f;
#pragma unroll
    for (int nt = 0; nt < 4; ++nt) {
      av[nt] = fmaxf(xAnch[g * 64 + nt * 16 + c] + bj[nt], 0.f);
      an2 += av[nt] * av[nt];
    }
    an2 = redC(an2);
    const float ainv = 1.f / fmaxf(sqrtf(an2), 1e-12f);
    if (q == 2)
#pragma unroll
      for (int nt = 0; nt < 4; ++nt)
        a_out[(size_t)bu * 64 + nt * 16 + c] = av[nt] * ainv;
  }
}

// ------- decoder anchor + per-graph loss, both streams, 4 graphs/block ---------
// W_dec row loaded once feeds 4 graphs x 2 streams (W L2 traffic /4 vs previous).
__global__ __launch_bounds__(256) void dec_kernel(
    const float* __restrict__ g1b, const float* __restrict__ g2b,
    const float* __restrict__ nd1b, const float* __restrict__ nd2b,
    const float* __restrict__ Wdec, const float* __restrict__ bdec,
    const float* __restrict__ feat1, const float* __restrict__ feat2,
    float* __restrict__ dArr1, float* __restrict__ dArr2)
{
  __shared__ float red[4][8];
  __shared__ float invs[8];
  const int t = threadIdx.x, lane = t & 63, wv = t >> 6;
  const int b0 = blockIdx.x * 4;
  float gva[4], gvb[4], nda[4], ndb[4];
#pragma unroll
  for (int gg = 0; gg < 4; ++gg) {
    gva[gg] = g1b[(size_t)(b0 + gg) * 64 + lane];
    gvb[gg] = g2b[(size_t)(b0 + gg) * 64 + lane];
    nda[gg] = nd1b[b0 + gg];
    ndb[gg] = nd2b[b0 + gg];
  }
  const int f0 = t, f1 = t + 256;
  const bool has1 = (f1 < FINN);
  float yA0[4] = {0.f, 0.f, 0.f, 0.f}, yA1[4] = {0.f, 0.f, 0.f, 0.f};
  float yB0[4] = {0.f, 0.f, 0.f, 0.f}, yB1[4] = {0.f, 0.f, 0.f, 0.f};
  for (int jj = 0; jj < 64; ++jj) {
    const float w0 = Wdec[jj * FINN + f0];
    const float w1 = has1 ? Wdec[jj * FINN + f1] : 0.f;
#pragma unroll
    for (int gg = 0; gg < 4; ++gg) {
      const float ga = __shfl(gva[gg], jj);
      const float gb = __shfl(gvb[gg], jj);
      yA0[gg] = fmaf(ga, w0, yA0[gg]);
      yA1[gg] = fmaf(ga, w1, yA1[gg]);
      yB0[gg] = fmaf(gb, w0, yB0[gg]);
      yB1[gg] = fmaf(gb, w1, yB1[gg]);
    }
  }
  const float bd0 = bdec[f0];
  const float bd1 = has1 ? bdec[f1] : 0.f;
  float aa0[4], aa1[4], ab0[4], ab1[4];
#pragma unroll
  for (int gg = 0; gg < 4; ++gg) {
    aa0[gg] = fmaxf(yA0[gg] * nda[gg] + bd0, 0.f);
    aa1[gg] = has1 ? fmaxf(yA1[gg] * nda[gg] + bd1, 0.f) : 0.f;
    ab0[gg] = fmaxf(yB0[gg] * ndb[gg] + bd0, 0.f);
    ab1[gg] = has1 ? fmaxf(yB1[gg] * ndb[gg] + bd1, 0.f) : 0.f;
    const float sA = waveSum(aa0[gg] * aa0[gg] + aa1[gg] * aa1[gg]);
    const float sB = waveSum(ab0[gg] * ab0[gg] + ab1[gg] * ab1[gg]);
    if (lane == 0) { red[wv][gg] = sA; red[wv][4 + gg] = sB; }
  }
  __syncthreads();
  if (t < 8) invs[t] = 1.f / fmaxf(sqrtf(red[0][t] + red[1][t] + red[2][t] + red[3][t]), 1e-12f);
  __syncthreads();
  float sdA[4], sdB[4];
#pragma unroll
  for (int gg = 0; gg < 4; ++gg) {
    const float* __restrict__ ori1 = feat1 + (size_t)(b0 + gg) * KK * FINN;  // row 0
    const float* __restrict__ ori2 = feat2 + (size_t)(b0 + gg) * KK * FINN;
    const float dA0 = aa0[gg] * invs[gg] - ori1[f0];
    const float dA1 = has1 ? (aa1[gg] * invs[gg] - ori1[f1]) : 0.f;
    const float dB0 = ab0[gg] * invs[4 + gg] - ori2[f0];
    const float dB1 = has1 ? (ab1[gg] * invs[4 + gg] - ori2[f1]) : 0.f;
    sdA[gg] = waveSum(dA0 * dA0 + dA1 * dA1);
    sdB[gg] = waveSum(dB0 * dB0 + dB1 * dB1);
  }
  __syncthreads();  // red reuse
  if (lane == 0) {
#pragma unroll
    for (int gg = 0; gg < 4; ++gg) { red[wv][gg] = sdA[gg]; red[wv][4 + gg] = sdB[gg]; }
  }
  __syncthreads();
  if (t < 4) dArr1[b0 + t] = red[0][t] + red[1][t] + red[2][t] + red[3][t];
  else if (t < 8) dArr2[b0 + t - 4] = red[0][t] + red[1][t] + red[2][t] + red[3][t];
}

// ---------------- bilinear discriminator (NO global atomics) ---------------------
__global__ __launch_bounds__(256) void bil_kernel(
    const float* __restrict__ pool1, const float* __restrict__ pool2,
    const float* __restrict__ pooln, const float* __restrict__ a1b,
    const float* __restrict__ a2b, const float* __restrict__ Wbil,
    const float* __restrict__ bbil, float* __restrict__ contr,
    float* __restrict__ tArr1, float* __restrict__ tArr2)
{
  const int tid = threadIdx.x, wv = tid >> 6, j = tid & 63;
  const int bu = blockIdx.x * 4 + wv;
  const float p1 = pool1[(size_t)bu * 64 + j];
  const float p2 = pool2[(size_t)bu * 64 + j];
  const float pn = pooln[(size_t)bu * 64 + j];
  const float A1 = a1b[(size_t)bu * 64 + j];
  const float A2 = a2b[(size_t)bu * 64 + j];
  float v1 = 0.f, v2 = 0.f, vn = 0.f;
  for (int jj = 0; jj < 64; ++jj) {
    const float wr = Wbil[jj * 64 + j];  // coalesced row
    v1 = fmaf(__shfl(p1, jj), wr, v1);
    v2 = fmaf(__shfl(p2, jj), wr, v2);
    vn = fmaf(__shfl(pn, jj), wr, vn);
  }
  const float d11 = waveSum(v1 * A1);
  const float d22 = waveSum(v2 * A2);
  const float dn1 = waveSum(vn * A1);
  const float dn2 = waveSum(vn * A2);
  if (j == 0) {
    const float bb = bbil[0];
    const float z11 = d11 + bb, z22 = d22 + bb, zn1 = dn1 + bb, zn2 = dn2 + bb;
    const float ps1 = 1.f / (1.f + expf(-z11));
    const float ps2 = 1.f / (1.f + expf(-z22));
    const float ns1 = 1.f / (1.f + expf(-zn1));
    const float ns2 = 1.f / (1.f + expf(-zn2));
    contr[bu] = (ns1 - ps1 + 1.f) * 0.5f + (ns2 - ps2 + 1.f) * 0.5f;
    tArr1[bu] = logsig(z11) + logsig(-zn1);
    tArr2[bu] = logsig(z22) + logsig(-zn2);
  }
}

// ---------------- reduction: 4 quantities x BB floats -> accs[0..3] (double) -----
__global__ __launch_bounds__(256) void reduce_kernel(const float* __restrict__ parts,
                                                     double* __restrict__ accs)
{
  __shared__ double sred[4];
  const int t = threadIdx.x, lane = t & 63, wv = t >> 6;
  const float* __restrict__ p = parts + (size_t)blockIdx.x * BB;
  double s = 0.0;
  for (int i = t; i < BB; i += 256) s += (double)p[i];
  s = waveSumD(s);
  if (lane == 0) sred[wv] = s;
  __syncthreads();
  if (t == 0) accs[blockIdx.x] = sred[0] + sred[1] + sred[2] + sred[3];
}

// ------- finalize + scores in one kernel (genw recomputed per thread, free) ------
__global__ void score_kernel(const double* __restrict__ accs,
                             const float* __restrict__ contr, float* __restrict__ out)
{
  const int i = blockIdx.x * blockDim.x + threadIdx.x;
  const double T1 = accs[0], T2 = accs[1], S1d = accs[2], S2d = accs[3];
  if (i == 0) {
    const double m1 = S1d / (double)BB, m2 = S2d / (double)BB;
    const double Lcon = -(m1 + m2) * 0.25;
    const double Lgen = (T1 + T2) / (2.0 * (double)BB * (double)FINN);
    out[0] = (float)(Lcon + 0.6 * Lgen);
  }
  const float genw = (float)((sqrt(T1) + sqrt(T2)) / (2.0 * sqrt((double)FINN)));
  if (i < BB) out[1 + i] = fmaf(0.6f, genw, contr[i]);
}

extern "C" void kernel_launch(void* const* d_in, const int* in_sizes, int n_in,
                              void* d_out, int out_size, void* d_ws, size_t ws_size,
                              hipStream_t stream)
{
  const float* feat_p1 = (const float*)d_in[0];
  const float* feat_p2 = (const float*)d_in[1];
  const float* feat_n  = (const float*)d_in[2];
  const float* w_p1 = (const float*)d_in[3];
  const float* w_p2 = (const float*)d_in[4];
  const float* w_n  = (const float*)d_in[5];
  const float* W_enc = (const float*)d_in[6];
  const float* b_enc = (const float*)d_in[7];
  const float* W_dec = (const float*)d_in[8];
  const float* b_dec = (const float*)d_in[9];
  const float* W_bil = (const float*)d_in[10];
  const float* b_bil = (const float*)d_in[11];
  const int* src_p1 = (const int*)d_in[12];
  const int* dst_p1 = (const int*)d_in[13];
  const int* src_p2 = (const int*)d_in[14];
  const int* dst_p2 = (const int*)d_in[15];
  const int* src_n  = (const int*)d_in[16];
  const int* dst_n  = (const int*)d_in[17];
  float* out = (float*)d_out;

  double* accs = (double*)d_ws;                          // [T1,T2,S1,S2]
  uint4* wsB = (uint4*)((char*)d_ws + 1024);             // 40960 B W_enc frags
  float* fws = (float*)((char*)d_ws + 49152);
  float* pool1 = fws;
  float* pool2 = pool1 + (size_t)BB * 64;
  float* pooln = pool2 + (size_t)BB * 64;
  float* a1 = pooln + (size_t)BB * 64;
  float* a2 = a1 + (size_t)BB * 64;
  float* g1 = a2 + (size_t)BB * 64;
  float* g2 = g1 + (size_t)BB * 64;
  float* nd01 = g2 + (size_t)BB * 64;
  float* nd02 = nd01 + BB;
  float* contr = nd02 + BB;
  float* parts = contr + BB;              // [dArr1 | dArr2 | tArr1 | tArr2], 4*BB
  float* dArr1 = parts;
  float* dArr2 = parts + BB;
  float* tArr1 = parts + 2 * BB;
  float* tArr2 = parts + 3 * BB;

  hipLaunchKernelGGL(prep_kernel, dim3(10), dim3(256), 0, stream, W_enc, wsB);
  hipLaunchKernelGGL(enc_kernel, dim3(3 * BB / 4), dim3(256), 0, stream,
                     feat_n, feat_p1, feat_p2,
                     w_n, w_p1, w_p2,
                     src_n, src_p1, src_p2,
                     dst_n, dst_p1, dst_p2,
                     wsB, b_enc,
                     pooln, pool1, pool2,
                     a1, a2, g1, g2, nd01, nd02);
  hipLaunchKernelGGL(dec_kernel, dim3(BB / 4), dim3(256), 0, stream,
                     g1, g2, nd01, nd02, W_dec, b_dec, feat_p1, feat_p2, dArr1, dArr2);
  hipLaunchKernelGGL(bil_kernel, dim3(BB / 4), dim3(256), 0, stream,
                     pool1, pool2, pooln, a1, a2, W_bil, b_bil, contr, tArr1, tArr2);
  hipLaunchKernelGGL(reduce_kernel, dim3(4), dim3(256), 0, stream, parts, accs);
  hipLaunchKernelGGL(score_kernel, dim3((BB + 255) / 256), dim3(256), 0, stream,
                     accs, contr, out);
}

// Round 3
// 551.828 us; speedup vs baseline: 1.1885x; 1.0130x over previous
//
#include <hip/hip_runtime.h>

// SL-GAD forward, MFMA version. Inputs/outputs FLOAT32. Output: [L, scores(8192)].
#define BB 8192
#define KK 16
#define EE 64
#define FINN 300

typedef __attribute__((ext_vector_type(8))) short short8;
typedef __attribute__((ext_vector_type(4))) float f32x4;

__device__ __forceinline__ unsigned short bf16r(float x) {  // f32 -> bf16 (RNE, native cvt)
  return __builtin_bit_cast(unsigned short, (__bf16)x);
}
__device__ __forceinline__ unsigned packbf(float a, float b) {  // 2xf32 -> bf16 pair
  return (unsigned)bf16r(a) | ((unsigned)bf16r(b) << 16);
}
__device__ __forceinline__ float redC(float v) {  // sum over lane bits 0..3 (col group)
  v += __shfl_xor(v, 1); v += __shfl_xor(v, 2);
  v += __shfl_xor(v, 4); v += __shfl_xor(v, 8);
  return v;
}
__device__ __forceinline__ float redQ(float v) {  // sum over quads (lane bits 4,5)
  v += __shfl_xor(v, 16); v += __shfl_xor(v, 32);
  return v;
}
__device__ __forceinline__ float waveSum(float v) {
#pragma unroll
  for (int off = 32; off; off >>= 1) v += __shfl_xor(v, off);
  return v;
}
__device__ __forceinline__ double waveSumD(double v) {
#pragma unroll
  for (int off = 32; off; off >>= 1) v += __shfl_xor(v, off);
  return v;
}
__device__ __forceinline__ float logsig(float z) {  // log(sigmoid(z)), stable
  return fminf(z, 0.f) - log1pf(expf(-fabsf(z)));
}

// prep: W_enc (300x64 f32) -> bf16 B-fragment layout [nt(4)][kstep(10)][lane(64)]x16B
__global__ void prep_kernel(const float* __restrict__ Wenc, uint4* __restrict__ wB) {
  const int id = blockIdx.x * 256 + threadIdx.x;
  if (id >= 2560) return;
  const int lane = id & 63;
  const int step = (id >> 6) % 10;
  const int nt = id / 640;
  const int n = nt * 16 + (lane & 15);
  const int kb = step * 32 + (lane >> 4) * 8;   // B[k=kb+j][n], j=0..7 per lane
  float f[8];
#pragma unroll
  for (int j2 = 0; j2 < 8; ++j2) {
    const int k = kb + j2;
    f[j2] = (k < FINN) ? Wenc[k * 64 + n] : 0.f;
  }
  uint4 o;
  o.x = packbf(f[0], f[1]); o.y = packbf(f[2], f[3]);
  o.z = packbf(f[4], f[5]); o.w = packbf(f[6], f[7]);
  wB[id] = o;
}

// ---------------- encoder: FUSED over the 3 feature streams --------------------
// grid = 3*2048; blockIdx>>11 selects stream. block = 256 = 4 waves.
// Feat staged in TWO 32-row half-tiles through one 20 KB buffer; each thread's
// 10 stage loads are batch-issued (Little's law: deep vmcnt pipeline), and the
// half-B loads are issued BEFORE GEMM-A so their latency hides under it (T14).
__global__ __launch_bounds__(256, 4) void enc_kernel(
    const float* __restrict__ fpn, const float* __restrict__ fp1, const float* __restrict__ fp2,
    const float* __restrict__ wn, const float* __restrict__ w1, const float* __restrict__ w2,
    const int* __restrict__ sn, const int* __restrict__ s1, const int* __restrict__ s2,
    const int* __restrict__ dn, const int* __restrict__ d1, const int* __restrict__ d2,
    const uint4* __restrict__ wB, const float* __restrict__ benc,
    float* __restrict__ pooln, float* __restrict__ pool1, float* __restrict__ pool2,
    float* __restrict__ a1o, float* __restrict__ a2o,
    float* __restrict__ g1o, float* __restrict__ g2o,
    float* __restrict__ nd1o, float* __restrict__ nd2o)
{
  __shared__ char smem[25856];
  // staging: 32 rows x 320 bf16 (640 B stride; cols 300..319 zero), XOR-swizzled:
  // dword index = row*160 + (d ^ ((row&7)<<2)); same swizzle on write and read.
  unsigned* featU = (unsigned*)smem;
  // phase 2 overlay:
  char* xBc = smem;                         // 16384 B: x bf16 B-frags [g][nt][lane]x16B
  float* AdjL = (float*)(smem + 16384);     // 4 x 256 f32 (dense adjacency, atomic build)
  char* AdjBc = smem + 20480;               // 4 x 16rows x 64B (bf16, s-padded to 32)
  float* coefL = (float*)(smem + 24576);    // 4 x 16 (Adj[0][s] * dinv[s])
  float* xAnch = (float*)(smem + 24832);    // 4 x 64 (x row 0 per graph, f32)

  const int tid = threadIdx.x, lane = tid & 63, wv = tid >> 6;
  const int q = lane >> 4, c = lane & 15;
  const int kf = blockIdx.x >> 11;          // stream: 0=n, 1=p1, 2=p2
  const int bg = blockIdx.x & 2047;
  const int b0 = bg * 4;

  const float* feat; const float* wedg; const int* src; const int* dst;
  float* pool_out; float* a_out; float* g_out; float* nd0_out;
  if (kf == 0) {
    feat = fpn; wedg = wn; src = sn; dst = dn;
    pool_out = pooln; a_out = nullptr; g_out = nullptr; nd0_out = nullptr;
  } else if (kf == 1) {
    feat = fp1; wedg = w1; src = s1; dst = d1;
    pool_out = pool1; a_out = a1o; g_out = g1o; nd0_out = nd1o;
  } else {
    feat = fp2; wedg = w2; src = s2; dst = d2;
    pool_out = pool2; a_out = a2o; g_out = g2o; nd0_out = nd2o;
  }

  // early independent loads: edges + bias (consumed in phase 2)
  const int bu = b0 + wv;
  const int se = src[bu * EE + lane];
  const int de = dst[bu * EE + lane];
  const float we = wedg[bu * EE + lane];
  float bj[4];
#pragma unroll
  for (int nt = 0; nt < 4; ++nt) bj[nt] = benc[nt * 16 + c];

  // W B-frags for this wave's n-tile, held in VGPRs (L2-resident)
  uint4 bfr[10];
  {
    const uint4* p = wB + (wv * 10) * 64 + lane;
#pragma unroll
    for (int s = 0; s < 10; ++s) bfr[s] = p[s * 64];
  }

  // staging geometry: thread -> (row = tid>>3, chunk base = tid&7), no division.
  const float4* gf = (const float4*)(feat + (size_t)b0 * (KK * FINN));
  const int srow = tid >> 3;                // 0..31 physical rows
  const int sc = tid & 7;
  const unsigned swz = (unsigned)((srow & 7) << 2);
  unsigned* frow = featU + srow * 160;

  float4 v[10];
  // ---- stage A: logical rows 0..31 — batch-issue all 10 loads, then pack+write
#pragma unroll
  for (int u = 0; u < 10; ++u) {
    const int c4 = sc + u * 8;
    if (c4 < 75) v[u] = gf[srow * 75 + c4];
  }
#pragma unroll
  for (int u = 0; u < 10; ++u) {
    const int c4 = sc + u * 8;
    if (c4 < 75) {
      uint2 o;
      o.x = packbf(v[u].x, v[u].y);
      o.y = packbf(v[u].z, v[u].w);
      *(uint2*)&frow[(unsigned)(c4 * 2) ^ swz] = o;
    }
  }
  // zero K-pad cols 300..319 (dwords 150..159; stays zero for half B)
  frow[(unsigned)(150 + sc) ^ swz] = 0;
  if (sc < 2) frow[(unsigned)(158 + sc) ^ swz] = 0;

  // ---- issue half-B loads NOW; they fly during barrier + GEMM-A
#pragma unroll
  for (int u = 0; u < 10; ++u) {
    const int c4 = sc + u * 8;
    if (c4 < 75) v[u] = gf[2400 + srow * 75 + c4];
  }
  __syncthreads();

  f32x4 acc[4];
#pragma unroll
  for (int m = 0; m < 4; ++m) acc[m] = (f32x4){0.f, 0.f, 0.f, 0.f};
  const int xr = (c & 7) << 4;  // byte swizzle: row = m*16+c, (row&7)<<4

  // GEMM half A: m-tiles 0,1 (physical rows 0..31)
#pragma unroll
  for (int s = 0; s < 10; ++s) {
    const short8 b8 = *(const short8*)&bfr[s];
#pragma unroll
    for (int m = 0; m < 2; ++m) {
      const short8 a8 = *(const short8*)(smem + (m * 16 + c) * 640 + ((s * 64 + q * 16) ^ xr));
      acc[m] = __builtin_amdgcn_mfma_f32_16x16x32_bf16(a8, b8, acc[m], 0, 0, 0);
    }
  }
  __syncthreads();  // half-A reads done before overwrite

  // ---- write half B (loads already landed / landing)
#pragma unroll
  for (int u = 0; u < 10; ++u) {
    const int c4 = sc + u * 8;
    if (c4 < 75) {
      uint2 o;
      o.x = packbf(v[u].x, v[u].y);
      o.y = packbf(v[u].z, v[u].w);
      *(uint2*)&frow[(unsigned)(c4 * 2) ^ swz] = o;
    }
  }
  __syncthreads();

  // GEMM half B: m-tiles 2,3 (physical rows 0..31)
#pragma unroll
  for (int s = 0; s < 10; ++s) {
    const short8 b8 = *(const short8*)&bfr[s];
#pragma unroll
    for (int m = 2; m < 4; ++m) {
      const short8 a8 = *(const short8*)(smem + ((m - 2) * 16 + c) * 640 + ((s * 64 + q * 16) ^ xr));
      acc[m] = __builtin_amdgcn_mfma_f32_16x16x32_bf16(a8, b8, acc[m], 0, 0, 0);
    }
  }
  __syncthreads();  // all featA reads done before overlay writes

  // epilogue: x -> bf16 B-frag layout for the spmm MFMA; x row0 f32 for anchor
#pragma unroll
  for (int m = 0; m < 4; ++m) {
    // C layout: col=lane&15 (in n-tile wv), row=q*4+r (in m-tile m); s=4q+r -> lane'=(q>>1)*16+c, jj=4(q&1)+r
    unsigned* dp = (unsigned*)(xBc + ((m * 4 + wv) * 64 + (q >> 1) * 16 + c) * 16 + (q & 1) * 8);
    dp[0] = packbf(acc[m][0], acc[m][1]);
    dp[1] = packbf(acc[m][2], acc[m][3]);
    if (q == 0) xAnch[m * 64 + wv * 16 + c] = acc[m][0];  // row 4*0+0 = node 0
  }
  {
    const uint4 z = {0, 0, 0, 0};
    for (int i = tid; i < 512; i += 256)            // zero xB K-pad lanes 32..63
      ((uint4*)xBc)[(i >> 5) * 64 + 32 + (i & 31)] = z;
    for (int i = tid; i < 512; i += 256)            // zero AdjL (4KB) + AdjB (4KB)
      ((uint4*)(smem + 16384))[i] = z;
  }
  __syncthreads();

  // -------- phase 2: wave = graph g = wv, lane = edge then (quad,col) roles ------
  const int g = wv;

  float dinv_reg = 0.f;  // lane k<16 ends holding dinv_src[k]
#pragma unroll
  for (int k = 0; k < KK; ++k) {
    const int cnt = __popcll(__ballot(se == k));
    if (lane == k) dinv_reg = rsqrtf(fmaxf((float)cnt, 1.f));
  }
  if (nd0_out) {
    const int cd0 = __popcll(__ballot(de == 0));
    if (lane == 0) nd0_out[bu] = rsqrtf(fmaxf((float)cd0, 1.f));
  }
  atomicAdd(&AdjL[g * 256 + de * 16 + se], we);  // dense adjacency build (ds_add, block-local)
  __threadfence_block();
  {
    // AdjL -> AdjB bf16 (A-frag rows, s-dim padded to 32 with zeros).
    // Encoder spmm must treat x[0]=0 (fz): zero column s=0 in AdjB only.
    const f32x4 v2 = *(const f32x4*)(AdjL + g * 256 + lane * 4);
    const float v0 = ((lane & 3) == 0) ? 0.f : v2[0];
    unsigned* w = (unsigned*)(AdjBc + g * 1024 + (lane >> 2) * 64 + (lane & 3) * 8);
    w[0] = packbf(v0, v2[1]);
    w[1] = packbf(v2[2], v2[3]);
  }
  if (g_out && lane < KK)  // coef[s] = Adj[0][s] * dinv_src[s] (raw Adj row 0)
    coefL[g * 16 + lane] = AdjL[g * 256 + lane] * dinv_reg;
  __threadfence_block();

  // spmm: agg(16x64) = Adj(16x16,pad32) @ x(16x64,pad32) as 4 MFMA
  const short8 aAdj = *(const short8*)(AdjBc + g * 1024 + c * 64 + q * 16);
  float h[4][4];
#pragma unroll
  for (int nt = 0; nt < 4; ++nt) {
    const short8 xb = *(const short8*)(xBc + ((g * 4 + nt) * 64 + lane) * 16);
    f32x4 cc = (f32x4){0.f, 0.f, 0.f, 0.f};
    cc = __builtin_amdgcn_mfma_f32_16x16x32_bf16(aAdj, xb, cc, 0, 0, 0);
#pragma unroll
    for (int r = 0; r < 4; ++r) h[nt][r] = fmaxf(cc[r] + bj[nt], 0.f);  // node 4q+r, col nt*16+c
  }

  // pool = l2n(sum_k h) (mean's 1/16 cancels in l2n)
  float pl[4];
#pragma unroll
  for (int nt = 0; nt < 4; ++nt)
    pl[nt] = redQ(h[nt][0] + h[nt][1] + h[nt][2] + h[nt][3]);
  float pn2 = redC(pl[0] * pl[0] + pl[1] * pl[1] + pl[2] * pl[2] + pl[3] * pl[3]);
  const float pinv = 1.f / fmaxf(sqrtf(pn2), 1e-12f);
  if (q == 0)
#pragma unroll
    for (int nt = 0; nt < 4; ++nt)
      pool_out[(size_t)bu * 64 + nt * 16 + c] = pl[nt] * pinv;

  if (g_out) {  // gather: g[j] = sum_s coef[s] * l2n(h)[s][j]
    float rnv[4];
#pragma unroll
    for (int r = 0; r < 4; ++r) {
      float s2 = redC(h[0][r] * h[0][r] + h[1][r] * h[1][r] +
                      h[2][r] * h[2][r] + h[3][r] * h[3][r]);
      rnv[r] = 1.f / fmaxf(sqrtf(s2), 1e-12f);
    }
    float gp[4] = {0.f, 0.f, 0.f, 0.f};
#pragma unroll
    for (int r = 0; r < 4; ++r) {
      const float cf = coefL[g * 16 + q * 4 + r] * rnv[r];
#pragma unroll
      for (int nt = 0; nt < 4; ++nt) gp[nt] = fmaf(cf, h[nt][r], gp[nt]);
    }
#pragma unroll
    for (int nt = 0; nt < 4; ++nt) gp[nt] = redQ(gp[nt]);
    if (q == 1)
#pragma unroll
      for (int nt = 0; nt < 4; ++nt)
        g_out[(size_t)bu * 64 + nt * 16 + c] = gp[nt];
  }
  if (a_out) {  // anchor = l2n(relu(x[0] + b))
    float av[4], an2 = 0.f;
#pragma unroll
    for (int nt = 0; nt < 4; ++nt) {
      av[nt] = fmaxf(xAnch[g * 64 + nt * 16 + c] + bj[nt], 0.f);
      an2 += av[nt] * av[nt];
    }
    an2 = redC(an2);
    const float ainv = 1.f / fmaxf(sqrtf(an2), 1e-12f);
    if (q == 2)
#pragma unroll
      for (int nt = 0; nt < 4; ++nt)
        a_out[(size_t)bu * 64 + nt * 16 + c] = av[nt] * ainv;
  }
}

// ------- decoder + bilinear discriminator fused: 4 graphs/block ----------------
__global__ __launch_bounds__(256) void decbil_kernel(
    const float* __restrict__ g1b, const float* __restrict__ g2b,
    const float* __restrict__ nd1b, const float* __restrict__ nd2b,
    const float* __restrict__ Wdec, const float* __restrict__ bdec,
    const float* __restrict__ feat1, const float* __restrict__ feat2,
    const float* __restrict__ pool1, const float* __restrict__ pool2,
    const float* __restrict__ pooln, const float* __restrict__ a1b,
    const float* __restrict__ a2b, const float* __restrict__ Wbil,
    const float* __restrict__ bbil,
    float* __restrict__ dArr1, float* __restrict__ dArr2,
    float* __restrict__ contr, float* __restrict__ tArr1, float* __restrict__ tArr2)
{
  __shared__ float red[4][8];
  __shared__ float invs[8];
  const int t = threadIdx.x, lane = t & 63, wv = t >> 6;
  const int b0 = blockIdx.x * 4;

  // ---------------- decoder part ----------------
  float gva[4], gvb[4], nda[4], ndb[4];
#pragma unroll
  for (int gg = 0; gg < 4; ++gg) {
    gva[gg] = g1b[(size_t)(b0 + gg) * 64 + lane];
    gvb[gg] = g2b[(size_t)(b0 + gg) * 64 + lane];
    nda[gg] = nd1b[b0 + gg];
    ndb[gg] = nd2b[b0 + gg];
  }
  const int f0 = t, f1 = t + 256;
  const bool has1 = (f1 < FINN);
  float yA0[4] = {0.f, 0.f, 0.f, 0.f}, yA1[4] = {0.f, 0.f, 0.f, 0.f};
  float yB0[4] = {0.f, 0.f, 0.f, 0.f}, yB1[4] = {0.f, 0.f, 0.f, 0.f};
  for (int jj = 0; jj < 64; ++jj) {
    const float w0 = Wdec[jj * FINN + f0];
    const float w1 = has1 ? Wdec[jj * FINN + f1] : 0.f;
#pragma unroll
    for (int gg = 0; gg < 4; ++gg) {
      const float ga = __shfl(gva[gg], jj);
      const float gb = __shfl(gvb[gg], jj);
      yA0[gg] = fmaf(ga, w0, yA0[gg]);
      yA1[gg] = fmaf(ga, w1, yA1[gg]);
      yB0[gg] = fmaf(gb, w0, yB0[gg]);
      yB1[gg] = fmaf(gb, w1, yB1[gg]);
    }
  }
  const float bd0 = bdec[f0];
  const float bd1 = has1 ? bdec[f1] : 0.f;
  float aa0[4], aa1[4], ab0[4], ab1[4];
#pragma unroll
  for (int gg = 0; gg < 4; ++gg) {
    aa0[gg] = fmaxf(yA0[gg] * nda[gg] + bd0, 0.f);
    aa1[gg] = has1 ? fmaxf(yA1[gg] * nda[gg] + bd1, 0.f) : 0.f;
    ab0[gg] = fmaxf(yB0[gg] * ndb[gg] + bd0, 0.f);
    ab1[gg] = has1 ? fmaxf(yB1[gg] * ndb[gg] + bd1, 0.f) : 0.f;
    const float sA = waveSum(aa0[gg] * aa0[gg] + aa1[gg] * aa1[gg]);
    const float sB = waveSum(ab0[gg] * ab0[gg] + ab1[gg] * ab1[gg]);
    if (lane == 0) { red[wv][gg] = sA; red[wv][4 + gg] = sB; }
  }
  __syncthreads();
  if (t < 8) invs[t] = 1.f / fmaxf(sqrtf(red[0][t] + red[1][t] + red[2][t] + red[3][t]), 1e-12f);
  __syncthreads();
  float sdA[4], sdB[4];
#pragma unroll
  for (int gg = 0; gg < 4; ++gg) {
    const float* __restrict__ ori1 = feat1 + (size_t)(b0 + gg) * KK * FINN;  // row 0
    const float* __restrict__ ori2 = feat2 + (size_t)(b0 + gg) * KK * FINN;
    const float dA0 = aa0[gg] * invs[gg] - ori1[f0];
    const float dA1 = has1 ? (aa1[gg] * invs[gg] - ori1[f1]) : 0.f;
    const float dB0 = ab0[gg] * invs[4 + gg] - ori2[f0];
    const float dB1 = has1 ? (ab1[gg] * invs[4 + gg] - ori2[f1]) : 0.f;
    sdA[gg] = waveSum(dA0 * dA0 + dA1 * dA1);
    sdB[gg] = waveSum(dB0 * dB0 + dB1 * dB1);
  }
  __syncthreads();  // red reuse
  if (lane == 0) {
#pragma unroll
    for (int gg = 0; gg < 4; ++gg) { red[wv][gg] = sdA[gg]; red[wv][4 + gg] = sdB[gg]; }
  }
  __syncthreads();
  if (t < 4) dArr1[b0 + t] = red[0][t] + red[1][t] + red[2][t] + red[3][t];
  else if (t < 8) dArr2[b0 + t - 4] = red[0][t] + red[1][t] + red[2][t] + red[3][t];

  // ---------------- bilinear part (wave wv = graph b0+wv) ----------------
  const int bu = b0 + wv, j = lane;
  const float p1 = pool1[(size_t)bu * 64 + j];
  const float p2 = pool2[(size_t)bu * 64 + j];
  const float pn = pooln[(size_t)bu * 64 + j];
  const float A1 = a1b[(size_t)bu * 64 + j];
  const float A2 = a2b[(size_t)bu * 64 + j];
  float v1 = 0.f, v2 = 0.f, vn = 0.f;
  for (int jj = 0; jj < 64; ++jj) {
    const float wr = Wbil[jj * 64 + j];  // coalesced row
    v1 = fmaf(__shfl(p1, jj), wr, v1);
    v2 = fmaf(__shfl(p2, jj), wr, v2);
    vn = fmaf(__shfl(pn, jj), wr, vn);
  }
  const float d11 = waveSum(v1 * A1);
  const float d22 = waveSum(v2 * A2);
  const float dn1 = waveSum(vn * A1);
  const float dn2 = waveSum(vn * A2);
  if (j == 0) {
    const float bb = bbil[0];
    const float z11 = d11 + bb, z22 = d22 + bb, zn1 = dn1 + bb, zn2 = dn2 + bb;
    const float ps1 = 1.f / (1.f + expf(-z11));
    const float ps2 = 1.f / (1.f + expf(-z22));
    const float ns1 = 1.f / (1.f + expf(-zn1));
    const float ns2 = 1.f / (1.f + expf(-zn2));
    contr[bu] = (ns1 - ps1 + 1.f) * 0.5f + (ns2 - ps2 + 1.f) * 0.5f;
    tArr1[bu] = logsig(z11) + logsig(-zn1);
    tArr2[bu] = logsig(z22) + logsig(-zn2);
  }
}

// ---------------- reduction: 4 quantities x BB floats -> accs[0..3] (double) -----
__global__ __launch_bounds__(256) void reduce_kernel(const float* __restrict__ parts,
                                                     double* __restrict__ accs)
{
  __shared__ double sred[4];
  const int t = threadIdx.x, lane = t & 63, wv = t >> 6;
  const float* __restrict__ p = parts + (size_t)blockIdx.x * BB;
  double s = 0.0;
  for (int i = t; i < BB; i += 256) s += (double)p[i];
  s = waveSumD(s);
  if (lane == 0) sred[wv] = s;
  __syncthreads();
  if (t == 0) accs[blockIdx.x] = sred[0] + sred[1] + sred[2] + sred[3];
}

// ------- finalize + scores in one kernel (genw recomputed per thread, free) ------
__global__ void score_kernel(const double* __restrict__ accs,
                             const float* __restrict__ contr, float* __restrict__ out)
{
  const int i = blockIdx.x * blockDim.x + threadIdx.x;
  const double T1 = accs[0], T2 = accs[1], S1d = accs[2], S2d = accs[3];
  if (i == 0) {
    const double m1 = S1d / (double)BB, m2 = S2d / (double)BB;
    const double Lcon = -(m1 + m2) * 0.25;
    const double Lgen = (T1 + T2) / (2.0 * (double)BB * (double)FINN);
    out[0] = (float)(Lcon + 0.6 * Lgen);
  }
  const float genw = (float)((sqrt(T1) + sqrt(T2)) / (2.0 * sqrt((double)FINN)));
  if (i < BB) out[1 + i] = fmaf(0.6f, genw, contr[i]);
}

extern "C" void kernel_launch(void* const* d_in, const int* in_sizes, int n_in,
                              void* d_out, int out_size, void* d_ws, size_t ws_size,
                              hipStream_t stream)
{
  const float* feat_p1 = (const float*)d_in[0];
  const float* feat_p2 = (const float*)d_in[1];
  const float* feat_n  = (const float*)d_in[2];
  const float* w_p1 = (const float*)d_in[3];
  const float* w_p2 = (const float*)d_in[4];
  const float* w_n  = (const float*)d_in[5];
  const float* W_enc = (const float*)d_in[6];
  const float* b_enc = (const float*)d_in[7];
  const float* W_dec = (const float*)d_in[8];
  const float* b_dec = (const float*)d_in[9];
  const float* W_bil = (const float*)d_in[10];
  const float* b_bil = (const float*)d_in[11];
  const int* src_p1 = (const int*)d_in[12];
  const int* dst_p1 = (const int*)d_in[13];
  const int* src_p2 = (const int*)d_in[14];
  const int* dst_p2 = (const int*)d_in[15];
  const int* src_n  = (const int*)d_in[16];
  const int* dst_n  = (const int*)d_in[17];
  float* out = (float*)d_out;

  double* accs = (double*)d_ws;                          // [T1,T2,S1,S2]
  uint4* wsB = (uint4*)((char*)d_ws + 1024);             // 40960 B W_enc frags
  float* fws = (float*)((char*)d_ws + 49152);
  float* pool1 = fws;
  float* pool2 = pool1 + (size_t)BB * 64;
  float* pooln = pool2 + (size_t)BB * 64;
  float* a1 = pooln + (size_t)BB * 64;
  float* a2 = a1 + (size_t)BB * 64;
  float* g1 = a2 + (size_t)BB * 64;
  float* g2 = g1 + (size_t)BB * 64;
  float* nd01 = g2 + (size_t)BB * 64;
  float* nd02 = nd01 + BB;
  float* contr = nd02 + BB;
  float* parts = contr + BB;              // [dArr1 | dArr2 | tArr1 | tArr2], 4*BB
  float* dArr1 = parts;
  float* dArr2 = parts + BB;
  float* tArr1 = parts + 2 * BB;
  float* tArr2 = parts + 3 * BB;

  hipLaunchKernelGGL(prep_kernel, dim3(10), dim3(256), 0, stream, W_enc, wsB);
  hipLaunchKernelGGL(enc_kernel, dim3(3 * BB / 4), dim3(256), 0, stream,
                     feat_n, feat_p1, feat_p2,
                     w_n, w_p1, w_p2,
                     src_n, src_p1, src_p2,
                     dst_n, dst_p1, dst_p2,
                     wsB, b_enc,
                     pooln, pool1, pool2,
                     a1, a2, g1, g2, nd01, nd02);
  hipLaunchKernelGGL(decbil_kernel, dim3(BB / 4), dim3(256), 0, stream,
                     g1, g2, nd01, nd02, W_dec, b_dec, feat_p1, feat_p2,
                     pool1, pool2, pooln, a1, a2, W_bil, b_bil,
                     dArr1, dArr2, contr, tArr1, tArr2);
  hipLaunchKernelGGL(reduce_kernel, dim3(4), dim3(256), 0, stream, parts, accs);
  hipLaunchKernelGGL(score_kernel, dim3((BB + 255) / 256), dim3(256), 0, stream,
                     accs, contr, out);
}